// Round 8
// baseline (366.226 us; speedup 1.0000x reference)
//
#include <hip/hip_runtime.h>
#include <hip/hip_bf16.h>

typedef __attribute__((ext_vector_type(8))) short short8;
typedef __attribute__((ext_vector_type(4))) float float4v;
typedef __attribute__((ext_vector_type(16))) float float16v;
typedef unsigned short u16;
typedef unsigned long long ull;

#define KD 1024

__device__ __forceinline__ u16 f2b(float f) {
    __hip_bfloat16 h = __float2bfloat16(f);
    return __builtin_bit_cast(u16, h);
}
__device__ __forceinline__ float b2f(u16 u) {
    unsigned x = ((unsigned)u) << 16;
    return __builtin_bit_cast(float, x);
}
__device__ __forceinline__ float lg_gamma(int h) {
    float gamma = 1.0f - exp2f(-5.0f - 0.5f * (float)h);
    return log2f(gamma);
}

// async global->LDS, 16B per lane; LDS dest is wave-uniform base + lane*16
__device__ __forceinline__ void async_cp16(const u16* g, u16* l) {
    __builtin_amdgcn_global_load_lds(
        (const __attribute__((address_space(1))) void*)g,
        (__attribute__((address_space(3))) void*)l,
        16, 0, 0);
}

// ---------------- fused converts ----------------
__global__ __launch_bounds__(256)
void cvt_all(const float* __restrict__ x, const float* __restrict__ wq,
             const float* __restrict__ wk, const float* __restrict__ wv,
             u16* __restrict__ xb, u16* __restrict__ wqkvb)
{
    int bid = blockIdx.x;
    if (bid < 4096) {
        long i = (long)bid * 1024 + threadIdx.x * 4;
        float4 v = *(const float4*)(x + i);
        ushort4 u;
        u.x = f2b(v.x); u.y = f2b(v.y); u.z = f2b(v.z); u.w = f2b(v.w);
        *(ushort4*)(xb + i) = u;
    } else {
        int wbid = bid - 4096;          // 0..1535
        int mtx = wbid >> 9;            // 0=wq 1=wk 2=wv
        int rem = wbid & 511;           // panel*16 + kg-quad
        int panel = rem >> 4;
        int lane = threadIdx.x & 63, wvid = threadIdx.x >> 6;
        int kg = (rem & 15) * 4 + wvid;
        int row = lane & 31, kh = lane >> 5;
        const float* src = (mtx == 0) ? wq : (mtx == 1) ? wk : wv;
        float sc = (mtx == 0) ? 0.125f : 1.0f;
        const float* srow = src + (size_t)(panel * 32 + row) * 1024 + kg * 16 + kh * 8;
        float4 a = *(const float4*)(srow);
        float4 b = *(const float4*)(srow + 4);
        short8 o;
        o[0] = (short)f2b(a.x * sc); o[1] = (short)f2b(a.y * sc);
        o[2] = (short)f2b(a.z * sc); o[3] = (short)f2b(a.w * sc);
        o[4] = (short)f2b(b.x * sc); o[5] = (short)f2b(b.y * sc);
        o[6] = (short)f2b(b.z * sc); o[7] = (short)f2b(b.w * sc);
        *(short8*)(wqkvb + (size_t)mtx * 1048576 + (size_t)panel * 32768 + kg * 512 + lane * 8) = o;
    }
}

// ---------------- NT GEMM ----------------
template<int MODE>
__global__ __launch_bounds__(256)
void gemm_nt(const u16* __restrict__ A, const u16* __restrict__ Bpk,
             u16* __restrict__ oQ, u16* __restrict__ oK,
             u16* __restrict__ oKt, u16* __restrict__ oVt,
             float* __restrict__ of, const float* __restrict__ bias)
{
    constexpr int TM = 128;
    constexpr int MI = 2;
    __shared__ __attribute__((aligned(16))) u16 Sh[16384];
    u16* As = Sh;
    const int tid = threadIdx.x;
    const int lane = tid & 63;
    const int wv = tid >> 6;
    const int wm = wv >> 1, wn = wv & 1;
    const int row32 = lane & 31, khalf = lane >> 5;
    const int lrow = lane >> 3, lseg = lane & 7;
    const int lin = blockIdx.x + gridDim.x * blockIdx.y;
    const int xcd = lin & 7, idx = lin >> 3;
    int m_tile, n_tile;
    m_tile = (idx & 3) + 4 * xcd;
    n_tile = idx >> 2;
    const int m0 = m_tile * TM, n0 = n_tile * 128;

    float16v acc[MI][2];
#pragma unroll
    for (int i = 0; i < MI; i++)
#pragma unroll
        for (int j = 0; j < 2; j++)
#pragma unroll
            for (int r = 0; r < 16; r++) acc[i][j][r] = 0.f;

    const int scol = (lseg ^ lrow) << 3;
    const u16* bp = Bpk + ((MODE == 1) ? (size_t)(m0 >> 11) * 1048576 : 0)
                  + (size_t)((n0 >> 5) + wn * 2) * 32768 + (size_t)lane * 8;

    for (int kt = 0; kt < KD; kt += 64) {
        __syncthreads();
#pragma unroll
        for (int i = 0; i < TM / 32; i++) {
            int r = wv * (TM / 4) + i * 8;
            async_cp16(A + (size_t)(m0 + r + lrow) * KD + kt + scol, &As[r * 64]);
        }
        short8 bgl[4][2];
#pragma unroll
        for (int ks = 0; ks < 4; ks++)
#pragma unroll
            for (int j = 0; j < 2; j++)
                bgl[ks][j] = *(const short8*)(bp + (size_t)j * 32768 + ((kt >> 4) + ks) * 512);
        __syncthreads();
#pragma unroll
        for (int ks = 0; ks < 4; ks++) {
            short8 af[MI];
#pragma unroll
            for (int i = 0; i < MI; i++) {
                int row = wm * (MI * 32) + i * 32 + row32;
                af[i] = *(const short8*)(&As[row * 64 + (((ks * 2 + khalf) ^ (row & 7)) << 3)]);
            }
#pragma unroll
            for (int i = 0; i < MI; i++)
#pragma unroll
                for (int j = 0; j < 2; j++)
                    acc[i][j] = __builtin_amdgcn_mfma_f32_32x32x16_bf16(af[i], bgl[ks][j], acc[i][j], 0, 0, 0);
        }
    }

    if (MODE == 0) {
        const int wsel = n0 >> 10;
        if (wsel <= 1) {
            u16* dst = (wsel == 0) ? oQ : oK;
#pragma unroll
            for (int i = 0; i < 2; i++)
#pragma unroll
                for (int j = 0; j < 2; j++) {
                    int gn = n0 + wn * 64 + j * 32 + row32;
                    int dd = gn & 63, hh = (gn >> 6) & 15;
#pragma unroll
                    for (int reg = 0; reg < 16; reg++) {
                        int m = m0 + wm * 64 + i * 32 + (reg & 3) + 8 * (reg >> 2) + 4 * khalf;
                        int b = m >> 11, t = m & 2047;
                        dst[(size_t)(b * 16 + hh) * 131072 + t * 64 + dd] = f2b(acc[i][j][reg]);
                    }
                }
        }
        if (wsel >= 1) {
            __syncthreads();
            u16* Tl = Sh + wv * 4096;
#pragma unroll
            for (int i = 0; i < 2; i++)
#pragma unroll
                for (int j = 0; j < 2; j++) {
                    int n_loc = j * 32 + row32;
#pragma unroll
                    for (int g = 0; g < 4; g++) {
                        int m4 = i * 32 + 8 * g + 4 * khalf;
                        ull pk = (ull)f2b(acc[i][j][4 * g]) | ((ull)f2b(acc[i][j][4 * g + 1]) << 16) |
                                 ((ull)f2b(acc[i][j][4 * g + 2]) << 32) | ((ull)f2b(acc[i][j][4 * g + 3]) << 48);
                        *(ull*)(&Tl[n_loc * 64 + (((m4 >> 3) ^ (n_loc & 7)) << 3) + (m4 & 7)]) = pk;
                    }
                }
            __syncthreads();
            int gnb = n0 + wn * 64;
            int hh = (gnb >> 6) & 15;
            int mb = m0 + wm * 64;
            int bh = (mb >> 11) * 16 + hh;
            int t0 = mb & 2047;
            u16* dstT = (wsel == 1) ? oKt : oVt;
            int rr = lane >> 3, ss = lane & 7;
#pragma unroll
            for (int g = 0; g < 8; g++) {
                int row = 8 * g + rr;
                short8 v = *(const short8*)(&Tl[row * 64 + ((ss ^ rr) << 3)]);
                *(short8*)(&dstT[(size_t)bh * 131072 + (size_t)row * 2048 + t0 + ss * 8]) = v;
            }
        }
    } else {
        int gn0 = n0 + wn * 64 + row32;
        float bv0 = bias[(m0 >> 11) * 1024 + gn0];
        float bv1 = bias[(m0 >> 11) * 1024 + gn0 + 32];
#pragma unroll
        for (int i = 0; i < 2; i++)
#pragma unroll
            for (int g = 0; g < 4; g++)
#pragma unroll
                for (int rr = 0; rr < 4; rr++) {
                    int reg = 4 * g + rr;
                    int m = m0 + wm * 64 + i * 32 + 8 * g + 4 * khalf + rr;
                    of[(size_t)m * 1024 + gn0] = acc[i][0][reg] + bv0;
                    of[(size_t)m * 1024 + gn0 + 32] = acc[i][1][reg] + bv1;
                }
    }
}

// ---------------- Pass A: per-chunk summary (REPS=1: real; REPS=8: PMC probe) ----
template<int REPS>
__global__ __launch_bounds__(256)
void chunk_state(const u16* __restrict__ Kt, const u16* __restrict__ Vt,
                 u16* __restrict__ U, float* __restrict__ stats)
{
    const int c = blockIdx.x, bh = blockIdx.y, h = bh & 15;
    const int tid = threadIdx.x, lane = tid & 63, w = tid >> 6;
    const int row16 = lane & 15, quad = lane >> 4;
    const float lg = lg_gamma(h);
    const size_t base = (size_t)bh * 131072;

    if (c == 0 && tid < 2) stats[2 * bh + tid] = 0.f;

    for (int rep = 0; rep < REPS; rep++) {
        float4v acc[4];
        float4v zero4 = {0.f, 0.f, 0.f, 0.f};
#pragma unroll
        for (int tn = 0; tn < 4; tn++) acc[tn] = zero4;

#pragma unroll
        for (int kb = 0; kb < 2; kb++) {
            short8 a = *(const short8*)(Vt + base + (size_t)(16 * w + row16) * 2048 + c * 64 + kb * 32 + quad * 8);
            short8 as;
            int e0 = 63 - (kb * 32 + quad * 8);
#pragma unroll
            for (int jj = 0; jj < 8; jj++) {
                float v = b2f((u16)a[jj]) * exp2f(lg * (float)(e0 - jj));
                as[jj] = (short)f2b(v);
            }
#pragma unroll
            for (int tn = 0; tn < 4; tn++) {
                short8 bfr = *(const short8*)(Kt + base + (size_t)(16 * tn + row16) * 2048 + c * 64 + kb * 32 + quad * 8);
                acc[tn] = __builtin_amdgcn_mfma_f32_16x16x32_bf16(as, bfr, acc[tn], 0, 0, 0);
            }
        }
        u16* up = U + ((size_t)bh * 32 + c) * 4096;
#pragma unroll
        for (int tn = 0; tn < 4; tn++)
#pragma unroll
            for (int r = 0; r < 4; r++)
                up[(16 * w + quad * 4 + r) * 64 + 16 * tn + row16] = f2b(acc[tn][r]);
    }
}

// ---------------- Pass C: intra + inter, fused one-level scan + GN sums ----
// (REPS=1: real; REPS=8: PMC probe into scratch)
template<int REPS>
__global__ __launch_bounds__(256)
void retention_chunk(const u16* __restrict__ Q, const u16* __restrict__ Kb,
                     const u16* __restrict__ Vt, const u16* __restrict__ U,
                     u16* __restrict__ Yb, float* __restrict__ stats)
{
    __shared__ __attribute__((aligned(16))) u16 Pl[4][16 * 72];
    __shared__ __attribute__((aligned(16))) u16 Sl[4096];
    __shared__ float red[8];
    const int c = blockIdx.x, bh = blockIdx.y, h = bh & 15;
    const int tid = threadIdx.x, lane = tid & 63, w = tid >> 6;
    const int row16 = lane & 15, quad = lane >> 4;
    const float lg = lg_gamma(h);
    const size_t base = (size_t)bh * 131072;
    float4v zero4 = {0.f, 0.f, 0.f, 0.f};

    for (int rep = 0; rep < REPS; rep++) {
        short8 qf[2];
#pragma unroll
        for (int kb = 0; kb < 2; kb++)
            qf[kb] = *(const short8*)(Q + base + (size_t)(c * 64 + 16 * w + row16) * 64 + kb * 32 + quad * 8);

        // ---- fused state scan (16 indep fp32 chains/thread) ----
        if (c != 0) {
            const float g64 = exp2f(lg * 64.0f);
            float sreg[16];
#pragma unroll
            for (int j = 0; j < 16; j++) sreg[j] = 0.f;
            for (int cp = 0; cp < c; cp++) {
                const u16* up = U + ((size_t)bh * 32 + cp) * 4096 + tid * 8;
                short8 u0 = *(const short8*)(up);
                short8 u1 = *(const short8*)(up + 2048);
#pragma unroll
                for (int jj = 0; jj < 8; jj++) {
                    sreg[jj]     = g64 * sreg[jj]     + b2f((u16)u0[jj]);
                    sreg[8 + jj] = g64 * sreg[8 + jj] + b2f((u16)u1[jj]);
                }
            }
#pragma unroll
            for (int j = 0; j < 2; j++) {
                int e0 = j * 2048 + tid * 8;
                int row = e0 >> 6, col8 = (e0 >> 3) & 7;
                short8 pk;
#pragma unroll
                for (int jj = 0; jj < 8; jj++) pk[jj] = (short)f2b(sreg[j * 8 + jj]);
                *(short8*)(&Sl[row * 64 + ((col8 ^ (row & 7)) << 3)]) = pk;
            }
        }

        float4v accp[4];
#pragma unroll
        for (int tn = 0; tn < 4; tn++) accp[tn] = zero4;
#pragma unroll
        for (int tn = 0; tn < 4; tn++)
#pragma unroll
            for (int kb = 0; kb < 2; kb++) {
                short8 kf = *(const short8*)(Kb + base + (size_t)(c * 64 + 16 * tn + row16) * 64 + kb * 32 + quad * 8);
                accp[tn] = __builtin_amdgcn_mfma_f32_16x16x32_bf16(qf[kb], kf, accp[tn], 0, 0, 0);
            }
#pragma unroll
        for (int tn = 0; tn < 4; tn++)
#pragma unroll
            for (int r = 0; r < 4; r++) {
                int a_loc = 16 * w + quad * 4 + r;
                int b_loc = 16 * tn + row16;
                int d = a_loc - b_loc;
                float v = (d >= 0) ? accp[tn][r] * exp2f(lg * (float)d) : 0.f;
                Pl[w][(quad * 4 + r) * 72 + b_loc] = f2b(v);
            }
        __syncthreads();

        short8 pf[2];
#pragma unroll
        for (int kb = 0; kb < 2; kb++)
            pf[kb] = *(const short8*)(&Pl[w][row16 * 72 + kb * 32 + quad * 8]);

        float4v acco[4], acci[4];
#pragma unroll
        for (int tn = 0; tn < 4; tn++) { acco[tn] = zero4; acci[tn] = zero4; }
#pragma unroll
        for (int tn = 0; tn < 4; tn++)
#pragma unroll
            for (int kb = 0; kb < 2; kb++) {
                short8 vf = *(const short8*)(Vt + base + (size_t)(16 * tn + row16) * 2048 + c * 64 + kb * 32 + quad * 8);
                acco[tn] = __builtin_amdgcn_mfma_f32_16x16x32_bf16(pf[kb], vf, acco[tn], 0, 0, 0);
                if (c != 0) {
                    int srow = 16 * tn + row16, scol8 = kb * 4 + quad;
                    short8 sf = *(const short8*)(&Sl[srow * 64 + ((scol8 ^ (srow & 7)) << 3)]);
                    acci[tn] = __builtin_amdgcn_mfma_f32_16x16x32_bf16(qf[kb], sf, acci[tn], 0, 0, 0);
                }
            }

        const int b = bh >> 4;
        float s = 0.f, s2 = 0.f;
#pragma unroll
        for (int tn = 0; tn < 4; tn++)
#pragma unroll
            for (int r = 0; r < 4; r++) {
                int a_loc = 16 * w + quad * 4 + r;
                float gi = exp2f(lg * (float)(a_loc + 1));
                int t = c * 64 + a_loc, d2 = 16 * tn + row16;
                float yv = acco[tn][r] + gi * acci[tn][r];
                u16 yq = f2b(yv);
                Yb[((size_t)(b * 2048 + t)) * 1024 + h * 64 + d2] = yq;
                float yr = b2f(yq);
                s += yr;
                s2 += yr * yr;
            }
#pragma unroll
        for (int off = 32; off; off >>= 1) {
            s += __shfl_down(s, off, 64);
            s2 += __shfl_down(s2, off, 64);
        }
        if (lane == 0) { red[w] = s; red[4 + w] = s2; }
        __syncthreads();
        if (tid == 0) {
            atomicAdd(&stats[2 * bh], red[0] + red[1] + red[2] + red[3]);
            atomicAdd(&stats[2 * bh + 1], red[4] + red[5] + red[6] + red[7]);
        }
        __syncthreads();
    }
}

// ---------------- GN fold (fully parallel) ----------------
__global__ __launch_bounds__(256)
void gn_fold(const float* __restrict__ wo, const float* __restrict__ stats,
             const float* __restrict__ gnw, const float* __restrict__ gnb,
             u16* __restrict__ wob2, float* __restrict__ bias)
{
    int bid = blockIdx.x;
    int lane = threadIdx.x & 63, wvid = threadIdx.x >> 6;
    if (bid < 512) {
        int seg = bid * 4 + wvid;
        int panel = seg >> 6, kg = seg & 63;
        int row = lane & 31, kh = lane >> 5;
        int c0 = kg * 16 + kh * 8;
        int hh = c0 >> 6;
        const float* srow = wo + (size_t)(panel * 32 + row) * 1024 + c0;
        float4 a = *(const float4*)(srow);
        float4 b = *(const float4*)(srow + 4);
        float4 w0 = *(const float4*)(gnw + c0);
        float4 w1 = *(const float4*)(gnw + c0 + 4);
        size_t off = (size_t)panel * 32768 + kg * 512 + lane * 8;
#pragma unroll
        for (int bb = 0; bb < 2; bb++) {
            int bh = bb * 16 + hh;
            float S = stats[2 * bh], S2 = stats[2 * bh + 1];
            float mu = S * (1.0f / 131072.f);
            float rsg = rsqrtf(S2 * (1.0f / 131072.f) - mu * mu + 1e-5f);
            short8 o;
            o[0] = (short)f2b(a.x * rsg * w0.x); o[1] = (short)f2b(a.y * rsg * w0.y);
            o[2] = (short)f2b(a.z * rsg * w0.z); o[3] = (short)f2b(a.w * rsg * w0.w);
            o[4] = (short)f2b(b.x * rsg * w1.x); o[5] = (short)f2b(b.y * rsg * w1.y);
            o[6] = (short)f2b(b.z * rsg * w1.z); o[7] = (short)f2b(b.w * rsg * w1.w);
            *(short8*)(wob2 + (size_t)bb * 1048576 + off) = o;
        }
    } else {
        int t = (bid - 512) * 4 + wvid;
        int bb = t >> 10, n = t & 1023;
        int c0 = lane * 16;
        int bh = bb * 16 + (c0 >> 6);
        float S = stats[2 * bh], S2 = stats[2 * bh + 1];
        float mu = S * (1.0f / 131072.f);
        float rsg = rsqrtf(S2 * (1.0f / 131072.f) - mu * mu + 1e-5f);
        const float* wrow = wo + (size_t)n * 1024 + c0;
        float acc = 0.f;
#pragma unroll
        for (int cc = 0; cc < 16; cc += 4) {
            float4 wo4 = *(const float4*)(wrow + cc);
            float4 w4 = *(const float4*)(gnw + c0 + cc);
            float4 b4 = *(const float4*)(gnb + c0 + cc);
            acc += (b4.x - mu * rsg * w4.x) * wo4.x + (b4.y - mu * rsg * w4.y) * wo4.y
                 + (b4.z - mu * rsg * w4.z) * wo4.z + (b4.w - mu * rsg * w4.w) * wo4.w;
        }
#pragma unroll
        for (int off = 32; off; off >>= 1) acc += __shfl_down(acc, off, 64);
        if (lane == 0) bias[t] = acc;
    }
}

extern "C" void kernel_launch(void* const* d_in, const int* in_sizes, int n_in,
                              void* d_out, int out_size, void* d_ws, size_t ws_size,
                              hipStream_t stream) {
    const float* x   = (const float*)d_in[0];
    const float* Wq  = (const float*)d_in[1];
    const float* Wk  = (const float*)d_in[2];
    const float* Wv  = (const float*)d_in[3];
    const float* Wo  = (const float*)d_in[4];
    const float* gnw = (const float*)d_in[5];
    const float* gnb = (const float*)d_in[6];
    float* out = (float*)d_out;
    char* ws = (char*)d_ws;

    u16*  xb    = (u16*)(ws + 0);           // 8 MB
    u16*  wqkvb = (u16*)(ws + 8388608);     // 6 MB
    u16*  Qs    = (u16*)(ws + 16777216);    // 8 MB
    u16*  Kb    = (u16*)(ws + 25165824);    // 8 MB
    u16*  Kt    = (u16*)(ws + 33554432);    // 8 MB
    u16*  Vt    = (u16*)(ws + 41943040);    // 8 MB
    u16*  U     = (u16*)(ws + 50331648);    // 8 MB
    u16*  Yb    = (u16*)(ws + 67108864);    // 8 MB
    u16*  wob2  = (u16*)(ws + 75497472);    // 4 MB
    float* bias = (float*)(ws + 79691776);  // 8 KB
    float* stats= (float*)(ws + 100663296); // 256 B
    // probe scratch
    u16*  U2    = (u16*)(ws + 134217728);   // 8 MB
    u16*  Yb2   = (u16*)(ws + 142606336);   // 8 MB
    float* st2  = (float*)(ws + 150994944); // 256 B

    cvt_all<<<5632, 256, 0, stream>>>(x, Wq, Wk, Wv, xb, wqkvb);

    gemm_nt<0><<<dim3(24, 32), 256, 0, stream>>>(xb, wqkvb, Qs, Kb, Kt, Vt, nullptr, nullptr);

    chunk_state<1><<<dim3(32, 32), 256, 0, stream>>>(Kt, Vt, U, stats);
    retention_chunk<1><<<dim3(32, 32), 256, 0, stream>>>(Qs, Kb, Vt, U, Yb, stats);

    gn_fold<<<1024, 256, 0, stream>>>(Wo, stats, gnw, gnb, wob2, bias);

    gemm_nt<1><<<dim3(8, 32), 256, 0, stream>>>(Yb, wob2, nullptr, nullptr, nullptr, nullptr, out, bias);

    // ---- PMC PROBES (this round only): x8 internal repeat makes each probe's
    // dispatch > 42us so it surfaces in rocprof top-5 with its own counters.
    chunk_state<8><<<dim3(32, 32), 256, 0, stream>>>(Kt, Vt, U2, st2);
    retention_chunk<8><<<dim3(32, 32), 256, 0, stream>>>(Qs, Kb, Vt, U, Yb2, st2);
}

// Round 9
// 179.891 us; speedup vs baseline: 2.0358x; 2.0358x over previous
//
#include <hip/hip_runtime.h>
#include <hip/hip_bf16.h>

typedef __attribute__((ext_vector_type(8))) short short8;
typedef __attribute__((ext_vector_type(4))) float float4v;
typedef __attribute__((ext_vector_type(16))) float float16v;
typedef unsigned short u16;
typedef unsigned long long ull;

#define KD 1024

__device__ __forceinline__ u16 f2b(float f) {
    __hip_bfloat16 h = __float2bfloat16(f);
    return __builtin_bit_cast(u16, h);
}
__device__ __forceinline__ float b2f(u16 u) {
    unsigned x = ((unsigned)u) << 16;
    return __builtin_bit_cast(float, x);
}
__device__ __forceinline__ float lg_gamma(int h) {
    float gamma = 1.0f - exp2f(-5.0f - 0.5f * (float)h);
    return log2f(gamma);
}

// async global->LDS, 16B per lane; LDS dest is wave-uniform base + lane*16
__device__ __forceinline__ void async_cp16(const u16* g, u16* l) {
    __builtin_amdgcn_global_load_lds(
        (const __attribute__((address_space(1))) void*)g,
        (__attribute__((address_space(3))) void*)l,
        16, 0, 0);
}

// ---------------- fused converts ----------------
__global__ __launch_bounds__(256)
void cvt_all(const float* __restrict__ x, const float* __restrict__ wq,
             const float* __restrict__ wk, const float* __restrict__ wv,
             u16* __restrict__ xb, u16* __restrict__ wqkvb)
{
    int bid = blockIdx.x;
    if (bid < 4096) {
        long i = (long)bid * 1024 + threadIdx.x * 4;
        float4 v = *(const float4*)(x + i);
        ushort4 u;
        u.x = f2b(v.x); u.y = f2b(v.y); u.z = f2b(v.z); u.w = f2b(v.w);
        *(ushort4*)(xb + i) = u;
    } else {
        int wbid = bid - 4096;          // 0..1535
        int mtx = wbid >> 9;            // 0=wq 1=wk 2=wv
        int rem = wbid & 511;           // panel*16 + kg-quad
        int panel = rem >> 4;
        int lane = threadIdx.x & 63, wvid = threadIdx.x >> 6;
        int kg = (rem & 15) * 4 + wvid;
        int row = lane & 31, kh = lane >> 5;
        const float* src = (mtx == 0) ? wq : (mtx == 1) ? wk : wv;
        float sc = (mtx == 0) ? 0.125f : 1.0f;
        const float* srow = src + (size_t)(panel * 32 + row) * 1024 + kg * 16 + kh * 8;
        float4 a = *(const float4*)(srow);
        float4 b = *(const float4*)(srow + 4);
        short8 o;
        o[0] = (short)f2b(a.x * sc); o[1] = (short)f2b(a.y * sc);
        o[2] = (short)f2b(a.z * sc); o[3] = (short)f2b(a.w * sc);
        o[4] = (short)f2b(b.x * sc); o[5] = (short)f2b(b.y * sc);
        o[6] = (short)f2b(b.z * sc); o[7] = (short)f2b(b.w * sc);
        *(short8*)(wqkvb + (size_t)mtx * 1048576 + (size_t)panel * 32768 + kg * 512 + lane * 8) = o;
    }
}

// ---------------- NT GEMM ----------------
template<int MODE>
__global__ __launch_bounds__(256)
void gemm_nt(const u16* __restrict__ A, const u16* __restrict__ Bpk,
             u16* __restrict__ oQ, u16* __restrict__ oK,
             u16* __restrict__ oKt, u16* __restrict__ oVt,
             float* __restrict__ of, const float* __restrict__ bias)
{
    constexpr int TM = 128;
    constexpr int MI = 2;
    __shared__ __attribute__((aligned(16))) u16 Sh[16384];
    u16* As = Sh;
    const int tid = threadIdx.x;
    const int lane = tid & 63;
    const int wv = tid >> 6;
    const int wm = wv >> 1, wn = wv & 1;
    const int row32 = lane & 31, khalf = lane >> 5;
    const int lrow = lane >> 3, lseg = lane & 7;
    const int lin = blockIdx.x + gridDim.x * blockIdx.y;
    const int xcd = lin & 7, idx = lin >> 3;
    int m_tile, n_tile;
    m_tile = (idx & 3) + 4 * xcd;
    n_tile = idx >> 2;
    const int m0 = m_tile * TM, n0 = n_tile * 128;

    float16v acc[MI][2];
#pragma unroll
    for (int i = 0; i < MI; i++)
#pragma unroll
        for (int j = 0; j < 2; j++)
#pragma unroll
            for (int r = 0; r < 16; r++) acc[i][j][r] = 0.f;

    const int scol = (lseg ^ lrow) << 3;
    const u16* bp = Bpk + ((MODE == 1) ? (size_t)(m0 >> 11) * 1048576 : 0)
                  + (size_t)((n0 >> 5) + wn * 2) * 32768 + (size_t)lane * 8;

    for (int kt = 0; kt < KD; kt += 64) {
        __syncthreads();
#pragma unroll
        for (int i = 0; i < TM / 32; i++) {
            int r = wv * (TM / 4) + i * 8;
            async_cp16(A + (size_t)(m0 + r + lrow) * KD + kt + scol, &As[r * 64]);
        }
        short8 bgl[4][2];
#pragma unroll
        for (int ks = 0; ks < 4; ks++)
#pragma unroll
            for (int j = 0; j < 2; j++)
                bgl[ks][j] = *(const short8*)(bp + (size_t)j * 32768 + ((kt >> 4) + ks) * 512);
        __syncthreads();
#pragma unroll
        for (int ks = 0; ks < 4; ks++) {
            short8 af[MI];
#pragma unroll
            for (int i = 0; i < MI; i++) {
                int row = wm * (MI * 32) + i * 32 + row32;
                af[i] = *(const short8*)(&As[row * 64 + (((ks * 2 + khalf) ^ (row & 7)) << 3)]);
            }
#pragma unroll
            for (int i = 0; i < MI; i++)
#pragma unroll
                for (int j = 0; j < 2; j++)
                    acc[i][j] = __builtin_amdgcn_mfma_f32_32x32x16_bf16(af[i], bgl[ks][j], acc[i][j], 0, 0, 0);
        }
    }

    if (MODE == 0) {
        const int wsel = n0 >> 10;
        if (wsel <= 1) {
            u16* dst = (wsel == 0) ? oQ : oK;
#pragma unroll
            for (int i = 0; i < 2; i++)
#pragma unroll
                for (int j = 0; j < 2; j++) {
                    int gn = n0 + wn * 64 + j * 32 + row32;
                    int dd = gn & 63, hh = (gn >> 6) & 15;
#pragma unroll
                    for (int reg = 0; reg < 16; reg++) {
                        int m = m0 + wm * 64 + i * 32 + (reg & 3) + 8 * (reg >> 2) + 4 * khalf;
                        int b = m >> 11, t = m & 2047;
                        dst[(size_t)(b * 16 + hh) * 131072 + t * 64 + dd] = f2b(acc[i][j][reg]);
                    }
                }
        }
        if (wsel >= 1) {
            __syncthreads();
            u16* Tl = Sh + wv * 4096;
#pragma unroll
            for (int i = 0; i < 2; i++)
#pragma unroll
                for (int j = 0; j < 2; j++) {
                    int n_loc = j * 32 + row32;
#pragma unroll
                    for (int g = 0; g < 4; g++) {
                        int m4 = i * 32 + 8 * g + 4 * khalf;
                        ull pk = (ull)f2b(acc[i][j][4 * g]) | ((ull)f2b(acc[i][j][4 * g + 1]) << 16) |
                                 ((ull)f2b(acc[i][j][4 * g + 2]) << 32) | ((ull)f2b(acc[i][j][4 * g + 3]) << 48);
                        *(ull*)(&Tl[n_loc * 64 + (((m4 >> 3) ^ (n_loc & 7)) << 3) + (m4 & 7)]) = pk;
                    }
                }
            __syncthreads();
            int gnb = n0 + wn * 64;
            int hh = (gnb >> 6) & 15;
            int mb = m0 + wm * 64;
            int bh = (mb >> 11) * 16 + hh;
            int t0 = mb & 2047;
            u16* dstT = (wsel == 1) ? oKt : oVt;
            int rr = lane >> 3, ss = lane & 7;
#pragma unroll
            for (int g = 0; g < 8; g++) {
                int row = 8 * g + rr;
                short8 v = *(const short8*)(&Tl[row * 64 + ((ss ^ rr) << 3)]);
                *(short8*)(&dstT[(size_t)bh * 131072 + (size_t)row * 2048 + t0 + ss * 8]) = v;
            }
        }
    } else {
        int gn0 = n0 + wn * 64 + row32;
        float bv0 = bias[(m0 >> 11) * 1024 + gn0];
        float bv1 = bias[(m0 >> 11) * 1024 + gn0 + 32];
#pragma unroll
        for (int i = 0; i < 2; i++)
#pragma unroll
            for (int g = 0; g < 4; g++)
#pragma unroll
                for (int rr = 0; rr < 4; rr++) {
                    int reg = 4 * g + rr;
                    int m = m0 + wm * 64 + i * 32 + 8 * g + 4 * khalf + rr;
                    of[(size_t)m * 1024 + gn0] = acc[i][0][reg] + bv0;
                    of[(size_t)m * 1024 + gn0 + 32] = acc[i][1][reg] + bv1;
                }
    }
}

// ---------------- Pass A: per-chunk summary; LDS-staged vector store ----------------
__global__ __launch_bounds__(256)
void chunk_state(const u16* __restrict__ Kt, const u16* __restrict__ Vt,
                 u16* __restrict__ U, float* __restrict__ stats)
{
    __shared__ __attribute__((aligned(16))) u16 Ul[64 * 72];
    const int c = blockIdx.x, bh = blockIdx.y, h = bh & 15;
    const int tid = threadIdx.x, lane = tid & 63, w = tid >> 6;
    const int row16 = lane & 15, quad = lane >> 4;
    const float lg = lg_gamma(h);
    const size_t base = (size_t)bh * 131072;

    if (c == 0 && tid < 2) stats[2 * bh + tid] = 0.f;

    float4v acc[4];
    float4v zero4 = {0.f, 0.f, 0.f, 0.f};
#pragma unroll
    for (int tn = 0; tn < 4; tn++) acc[tn] = zero4;

#pragma unroll
    for (int kb = 0; kb < 2; kb++) {
        short8 a = *(const short8*)(Vt + base + (size_t)(16 * w + row16) * 2048 + c * 64 + kb * 32 + quad * 8);
        short8 as;
        int e0 = 63 - (kb * 32 + quad * 8);
#pragma unroll
        for (int jj = 0; jj < 8; jj++) {
            float v = b2f((u16)a[jj]) * exp2f(lg * (float)(e0 - jj));
            as[jj] = (short)f2b(v);
        }
#pragma unroll
        for (int tn = 0; tn < 4; tn++) {
            short8 bfr = *(const short8*)(Kt + base + (size_t)(16 * tn + row16) * 2048 + c * 64 + kb * 32 + quad * 8);
            acc[tn] = __builtin_amdgcn_mfma_f32_16x16x32_bf16(as, bfr, acc[tn], 0, 0, 0);
        }
    }
    // stage tile in LDS (padded rows), then two short8 (32B) per thread to global
#pragma unroll
    for (int tn = 0; tn < 4; tn++)
#pragma unroll
        for (int r = 0; r < 4; r++)
            Ul[(16 * w + quad * 4 + r) * 72 + 16 * tn + row16] = f2b(acc[tn][r]);
    __syncthreads();
    {
        int row = tid >> 2, cs = (tid & 3) * 16;
        u16* gp = U + ((size_t)bh * 32 + c) * 4096 + row * 64 + cs;
        short8 v0 = *(const short8*)(&Ul[row * 72 + cs]);
        short8 v1 = *(const short8*)(&Ul[row * 72 + cs + 8]);
        *(short8*)(gp) = v0;
        *(short8*)(gp + 8) = v1;
    }
}

// ---------------- Pass C: intra + inter, fused scan (4x unrolled, MLP-8) + GN sums;
//                  LDS-staged vector Y store ----------------
__global__ __launch_bounds__(256)
void retention_chunk(const u16* __restrict__ Q, const u16* __restrict__ Kb,
                     const u16* __restrict__ Vt, const u16* __restrict__ U,
                     u16* __restrict__ Yb, float* __restrict__ stats)
{
    __shared__ __attribute__((aligned(16))) u16 Pl[4][16 * 72];   // P tiles; reused as Y tile
    __shared__ __attribute__((aligned(16))) u16 Sl[4096];         // S^T, XOR-swizzled
    __shared__ float red[8];
    const int c = blockIdx.x, bh = blockIdx.y, h = bh & 15;
    const int tid = threadIdx.x, lane = tid & 63, w = tid >> 6;
    const int row16 = lane & 15, quad = lane >> 4;
    const float lg = lg_gamma(h);
    const size_t base = (size_t)bh * 131072;
    float4v zero4 = {0.f, 0.f, 0.f, 0.f};

    short8 qf[2];
#pragma unroll
    for (int kb = 0; kb < 2; kb++)
        qf[kb] = *(const short8*)(Q + base + (size_t)(c * 64 + 16 * w + row16) * 64 + kb * 32 + quad * 8);

    // ---- fused state scan: 4x unrolled, 8 loads in flight per step ----
    if (c != 0) {
        const float g1 = exp2f(lg * 64.0f);
        const float g2 = g1 * g1, g3 = g2 * g1, g4 = g2 * g2;
        float sreg[16];
#pragma unroll
        for (int j = 0; j < 16; j++) sreg[j] = 0.f;
        const u16* ub = U + (size_t)bh * 131072 + tid * 8;
        int cp = 0;
        for (; cp + 4 <= c; cp += 4) {
            const u16* p = ub + (size_t)cp * 4096;
            short8 a0 = *(const short8*)(p);
            short8 a1 = *(const short8*)(p + 2048);
            short8 b0 = *(const short8*)(p + 4096);
            short8 b1 = *(const short8*)(p + 4096 + 2048);
            short8 c0 = *(const short8*)(p + 8192);
            short8 c1 = *(const short8*)(p + 8192 + 2048);
            short8 d0 = *(const short8*)(p + 12288);
            short8 d1 = *(const short8*)(p + 12288 + 2048);
#pragma unroll
            for (int jj = 0; jj < 8; jj++) {
                float t0 = b2f((u16)a0[jj]) * g3 + b2f((u16)b0[jj]) * g2
                         + b2f((u16)c0[jj]) * g1 + b2f((u16)d0[jj]);
                float t1 = b2f((u16)a1[jj]) * g3 + b2f((u16)b1[jj]) * g2
                         + b2f((u16)c1[jj]) * g1 + b2f((u16)d1[jj]);
                sreg[jj]     = sreg[jj] * g4 + t0;
                sreg[8 + jj] = sreg[8 + jj] * g4 + t1;
            }
        }
        for (; cp < c; cp++) {
            const u16* p = ub + (size_t)cp * 4096;
            short8 u0 = *(const short8*)(p);
            short8 u1 = *(const short8*)(p + 2048);
#pragma unroll
            for (int jj = 0; jj < 8; jj++) {
                sreg[jj]     = g1 * sreg[jj]     + b2f((u16)u0[jj]);
                sreg[8 + jj] = g1 * sreg[8 + jj] + b2f((u16)u1[jj]);
            }
        }
#pragma unroll
        for (int j = 0; j < 2; j++) {
            int e0 = j * 2048 + tid * 8;
            int row = e0 >> 6, col8 = (e0 >> 3) & 7;
            short8 pk;
#pragma unroll
            for (int jj = 0; jj < 8; jj++) pk[jj] = (short)f2b(sreg[j * 8 + jj]);
            *(short8*)(&Sl[row * 64 + ((col8 ^ (row & 7)) << 3)]) = pk;
        }
    }

    // Phase 1: P = (Q*0.125) K^T
    float4v accp[4];
#pragma unroll
    for (int tn = 0; tn < 4; tn++) accp[tn] = zero4;
#pragma unroll
    for (int tn = 0; tn < 4; tn++)
#pragma unroll
        for (int kb = 0; kb < 2; kb++) {
            short8 kf = *(const short8*)(Kb + base + (size_t)(c * 64 + 16 * tn + row16) * 64 + kb * 32 + quad * 8);
            accp[tn] = __builtin_amdgcn_mfma_f32_16x16x32_bf16(qf[kb], kf, accp[tn], 0, 0, 0);
        }
#pragma unroll
    for (int tn = 0; tn < 4; tn++)
#pragma unroll
        for (int r = 0; r < 4; r++) {
            int a_loc = 16 * w + quad * 4 + r;
            int b_loc = 16 * tn + row16;
            int d = a_loc - b_loc;
            float v = (d >= 0) ? accp[tn][r] * exp2f(lg * (float)d) : 0.f;
            Pl[w][(quad * 4 + r) * 72 + b_loc] = f2b(v);
        }
    __syncthreads();

    short8 pf[2];
#pragma unroll
    for (int kb = 0; kb < 2; kb++)
        pf[kb] = *(const short8*)(&Pl[w][row16 * 72 + kb * 32 + quad * 8]);

    float4v acco[4], acci[4];
#pragma unroll
    for (int tn = 0; tn < 4; tn++) { acco[tn] = zero4; acci[tn] = zero4; }
#pragma unroll
    for (int tn = 0; tn < 4; tn++)
#pragma unroll
        for (int kb = 0; kb < 2; kb++) {
            short8 vf = *(const short8*)(Vt + base + (size_t)(16 * tn + row16) * 2048 + c * 64 + kb * 32 + quad * 8);
            acco[tn] = __builtin_amdgcn_mfma_f32_16x16x32_bf16(pf[kb], vf, acco[tn], 0, 0, 0);
            if (c != 0) {
                int srow = 16 * tn + row16, scol8 = kb * 4 + quad;
                short8 sf = *(const short8*)(&Sl[srow * 64 + ((scol8 ^ (srow & 7)) << 3)]);
                acci[tn] = __builtin_amdgcn_mfma_f32_16x16x32_bf16(qf[kb], sf, acci[tn], 0, 0, 0);
            }
        }

    // ---- epilogue: stage Y tile in LDS (reuse Pl), GN partial sums, vector store ----
    __syncthreads();                       // all pf/sf reads done; Pl/Sl now dead
    u16* Yl = &Pl[0][0];                   // 64 x 72 u16 tile
    const int b = bh >> 4;
    float s = 0.f, s2 = 0.f;
#pragma unroll
    for (int tn = 0; tn < 4; tn++)
#pragma unroll
        for (int r = 0; r < 4; r++) {
            int a_loc = 16 * w + quad * 4 + r;
            float gi = exp2f(lg * (float)(a_loc + 1));
            int d2 = 16 * tn + row16;
            float yv = acco[tn][r] + gi * acci[tn][r];
            u16 yq = f2b(yv);
            Yl[a_loc * 72 + d2] = yq;
            float yr = b2f(yq);
            s += yr;
            s2 += yr * yr;
        }
    __syncthreads();
    {
        int row = tid >> 2, cs = (tid & 3) * 16;
        u16* gp = Yb + ((size_t)(b * 2048 + c * 64 + row)) * 1024 + h * 64 + cs;
        short8 v0 = *(const short8*)(&Yl[row * 72 + cs]);
        short8 v1 = *(const short8*)(&Yl[row * 72 + cs + 8]);
        *(short8*)(gp) = v0;
        *(short8*)(gp + 8) = v1;
    }
    // fused GN partial sums: wave reduce -> LDS -> one atomic pair per block
#pragma unroll
    for (int off = 32; off; off >>= 1) {
        s += __shfl_down(s, off, 64);
        s2 += __shfl_down(s2, off, 64);
    }
    if (lane == 0) { red[w] = s; red[4 + w] = s2; }
    __syncthreads();
    if (tid == 0) {
        atomicAdd(&stats[2 * bh], red[0] + red[1] + red[2] + red[3]);
        atomicAdd(&stats[2 * bh + 1], red[4] + red[5] + red[6] + red[7]);
    }
}

// ---------------- GN fold (fully parallel) ----------------
__global__ __launch_bounds__(256)
void gn_fold(const float* __restrict__ wo, const float* __restrict__ stats,
             const float* __restrict__ gnw, const float* __restrict__ gnb,
             u16* __restrict__ wob2, float* __restrict__ bias)
{
    int bid = blockIdx.x;
    int lane = threadIdx.x & 63, wvid = threadIdx.x >> 6;
    if (bid < 512) {
        int seg = bid * 4 + wvid;
        int panel = seg >> 6, kg = seg & 63;
        int row = lane & 31, kh = lane >> 5;
        int c0 = kg * 16 + kh * 8;
        int hh = c0 >> 6;
        const float* srow = wo + (size_t)(panel * 32 + row) * 1024 + c0;
        float4 a = *(const float4*)(srow);
        float4 b = *(const float4*)(srow + 4);
        float4 w0 = *(const float4*)(gnw + c0);
        float4 w1 = *(const float4*)(gnw + c0 + 4);
        size_t off = (size_t)panel * 32768 + kg * 512 + lane * 8;
#pragma unroll
        for (int bb = 0; bb < 2; bb++) {
            int bh = bb * 16 + hh;
            float S = stats[2 * bh], S2 = stats[2 * bh + 1];
            float mu = S * (1.0f / 131072.f);
            float rsg = rsqrtf(S2 * (1.0f / 131072.f) - mu * mu + 1e-5f);
            short8 o;
            o[0] = (short)f2b(a.x * rsg * w0.x); o[1] = (short)f2b(a.y * rsg * w0.y);
            o[2] = (short)f2b(a.z * rsg * w0.z); o[3] = (short)f2b(a.w * rsg * w0.w);
            o[4] = (short)f2b(b.x * rsg * w1.x); o[5] = (short)f2b(b.y * rsg * w1.y);
            o[6] = (short)f2b(b.z * rsg * w1.z); o[7] = (short)f2b(b.w * rsg * w1.w);
            *(short8*)(wob2 + (size_t)bb * 1048576 + off) = o;
        }
    } else {
        int t = (bid - 512) * 4 + wvid;
        int bb = t >> 10, n = t & 1023;
        int c0 = lane * 16;
        int bh = bb * 16 + (c0 >> 6);
        float S = stats[2 * bh], S2 = stats[2 * bh + 1];
        float mu = S * (1.0f / 131072.f);
        float rsg = rsqrtf(S2 * (1.0f / 131072.f) - mu * mu + 1e-5f);
        const float* wrow = wo + (size_t)n * 1024 + c0;
        float acc = 0.f;
#pragma unroll
        for (int cc = 0; cc < 16; cc += 4) {
            float4 wo4 = *(const float4*)(wrow + cc);
            float4 w4 = *(const float4*)(gnw + c0 + cc);
            float4 b4 = *(const float4*)(gnb + c0 + cc);
            acc += (b4.x - mu * rsg * w4.x) * wo4.x + (b4.y - mu * rsg * w4.y) * wo4.y
                 + (b4.z - mu * rsg * w4.z) * wo4.z + (b4.w - mu * rsg * w4.w) * wo4.w;
        }
#pragma unroll
        for (int off = 32; off; off >>= 1) acc += __shfl_down(acc, off, 64);
        if (lane == 0) bias[t] = acc;
    }
}

extern "C" void kernel_launch(void* const* d_in, const int* in_sizes, int n_in,
                              void* d_out, int out_size, void* d_ws, size_t ws_size,
                              hipStream_t stream) {
    const float* x   = (const float*)d_in[0];
    const float* Wq  = (const float*)d_in[1];
    const float* Wk  = (const float*)d_in[2];
    const float* Wv  = (const float*)d_in[3];
    const float* Wo  = (const float*)d_in[4];
    const float* gnw = (const float*)d_in[5];
    const float* gnb = (const float*)d_in[6];
    float* out = (float*)d_out;
    char* ws = (char*)d_ws;

    u16*  xb    = (u16*)(ws + 0);           // 8 MB
    u16*  wqkvb = (u16*)(ws + 8388608);     // 6 MB
    u16*  Qs    = (u16*)(ws + 16777216);    // 8 MB
    u16*  Kb    = (u16*)(ws + 25165824);    // 8 MB
    u16*  Kt    = (u16*)(ws + 33554432);    // 8 MB
    u16*  Vt    = (u16*)(ws + 41943040);    // 8 MB
    u16*  U     = (u16*)(ws + 50331648);    // 8 MB
    u16*  Yb    = (u16*)(ws + 67108864);    // 8 MB
    u16*  wob2  = (u16*)(ws + 75497472);    // 4 MB
    float* bias = (float*)(ws + 79691776);  // 8 KB
    float* stats= (float*)(ws + 100663296); // 256 B

    cvt_all<<<5632, 256, 0, stream>>>(x, Wq, Wk, Wv, xb, wqkvb);

    gemm_nt<0><<<dim3(24, 32), 256, 0, stream>>>(xb, wqkvb, Qs, Kb, Kt, Vt, nullptr, nullptr);

    chunk_state<<<dim3(32, 32), 256, 0, stream>>>(Kt, Vt, U, stats);
    retention_chunk<<<dim3(32, 32), 256, 0, stream>>>(Qs, Kb, Vt, U, Yb, stats);

    gn_fold<<<1024, 256, 0, stream>>>(Wo, stats, gnw, gnb, wob2, bias);

    gemm_nt<1><<<dim3(8, 32), 256, 0, stream>>>(Yb, wob2, nullptr, nullptr, nullptr, nullptr, out, bias);
}

// Round 10
// 171.685 us; speedup vs baseline: 2.1331x; 1.0478x over previous
//
#include <hip/hip_runtime.h>
#include <hip/hip_bf16.h>

typedef __attribute__((ext_vector_type(8))) short short8;
typedef __attribute__((ext_vector_type(4))) float float4v;
typedef __attribute__((ext_vector_type(16))) float float16v;
typedef unsigned short u16;
typedef unsigned long long ull;

#define KD 1024

__device__ __forceinline__ u16 f2b(float f) {
    __hip_bfloat16 h = __float2bfloat16(f);
    return __builtin_bit_cast(u16, h);
}
__device__ __forceinline__ float b2f(u16 u) {
    unsigned x = ((unsigned)u) << 16;
    return __builtin_bit_cast(float, x);
}
__device__ __forceinline__ float lg_gamma(int h) {
    float gamma = 1.0f - exp2f(-5.0f - 0.5f * (float)h);
    return log2f(gamma);
}

// async global->LDS, 16B per lane; LDS dest is wave-uniform base + lane*16
__device__ __forceinline__ void async_cp16(const u16* g, u16* l) {
    __builtin_amdgcn_global_load_lds(
        (const __attribute__((address_space(1))) void*)g,
        (__attribute__((address_space(3))) void*)l,
        16, 0, 0);
}

// ---------------- fused converts ----------------
__global__ __launch_bounds__(256)
void cvt_all(const float* __restrict__ x, const float* __restrict__ wq,
             const float* __restrict__ wk, const float* __restrict__ wv,
             u16* __restrict__ xb, u16* __restrict__ wqkvb)
{
    int bid = blockIdx.x;
    if (bid < 4096) {
        long i = (long)bid * 1024 + threadIdx.x * 4;
        float4 v = *(const float4*)(x + i);
        ushort4 u;
        u.x = f2b(v.x); u.y = f2b(v.y); u.z = f2b(v.z); u.w = f2b(v.w);
        *(ushort4*)(xb + i) = u;
    } else {
        int wbid = bid - 4096;          // 0..1535
        int mtx = wbid >> 9;            // 0=wq 1=wk 2=wv
        int rem = wbid & 511;           // panel*16 + kg-quad
        int panel = rem >> 4;
        int lane = threadIdx.x & 63, wvid = threadIdx.x >> 6;
        int kg = (rem & 15) * 4 + wvid;
        int row = lane & 31, kh = lane >> 5;
        const float* src = (mtx == 0) ? wq : (mtx == 1) ? wk : wv;
        float sc = (mtx == 0) ? 0.125f : 1.0f;
        const float* srow = src + (size_t)(panel * 32 + row) * 1024 + kg * 16 + kh * 8;
        float4 a = *(const float4*)(srow);
        float4 b = *(const float4*)(srow + 4);
        short8 o;
        o[0] = (short)f2b(a.x * sc); o[1] = (short)f2b(a.y * sc);
        o[2] = (short)f2b(a.z * sc); o[3] = (short)f2b(a.w * sc);
        o[4] = (short)f2b(b.x * sc); o[5] = (short)f2b(b.y * sc);
        o[6] = (short)f2b(b.z * sc); o[7] = (short)f2b(b.w * sc);
        *(short8*)(wqkvb + (size_t)mtx * 1048576 + (size_t)panel * 32768 + kg * 512 + lane * 8) = o;
    }
}

// ---------------- NT GEMM ----------------
template<int MODE>
__global__ __launch_bounds__(256)
void gemm_nt(const u16* __restrict__ A, const u16* __restrict__ Bpk,
             u16* __restrict__ oQ, u16* __restrict__ oK,
             u16* __restrict__ oKt, u16* __restrict__ oVt,
             float* __restrict__ of, const float* __restrict__ bias)
{
    constexpr int TM = 128;
    constexpr int MI = 2;
    __shared__ __attribute__((aligned(16))) u16 Sh[16384];
    u16* As = Sh;
    const int tid = threadIdx.x;
    const int lane = tid & 63;
    const int wv = tid >> 6;
    const int wm = wv >> 1, wn = wv & 1;
    const int row32 = lane & 31, khalf = lane >> 5;
    const int lrow = lane >> 3, lseg = lane & 7;
    const int lin = blockIdx.x + gridDim.x * blockIdx.y;
    const int xcd = lin & 7, idx = lin >> 3;
    int m_tile, n_tile;
    m_tile = (idx & 3) + 4 * xcd;
    n_tile = idx >> 2;
    const int m0 = m_tile * TM, n0 = n_tile * 128;

    float16v acc[MI][2];
#pragma unroll
    for (int i = 0; i < MI; i++)
#pragma unroll
        for (int j = 0; j < 2; j++)
#pragma unroll
            for (int r = 0; r < 16; r++) acc[i][j][r] = 0.f;

    const int scol = (lseg ^ lrow) << 3;
    const u16* bp = Bpk + ((MODE == 1) ? (size_t)(m0 >> 11) * 1048576 : 0)
                  + (size_t)((n0 >> 5) + wn * 2) * 32768 + (size_t)lane * 8;

    for (int kt = 0; kt < KD; kt += 64) {
        __syncthreads();
#pragma unroll
        for (int i = 0; i < TM / 32; i++) {
            int r = wv * (TM / 4) + i * 8;
            async_cp16(A + (size_t)(m0 + r + lrow) * KD + kt + scol, &As[r * 64]);
        }
        short8 bgl[4][2];
#pragma unroll
        for (int ks = 0; ks < 4; ks++)
#pragma unroll
            for (int j = 0; j < 2; j++)
                bgl[ks][j] = *(const short8*)(bp + (size_t)j * 32768 + ((kt >> 4) + ks) * 512);
        __syncthreads();
#pragma unroll
        for (int ks = 0; ks < 4; ks++) {
            short8 af[MI];
#pragma unroll
            for (int i = 0; i < MI; i++) {
                int row = wm * (MI * 32) + i * 32 + row32;
                af[i] = *(const short8*)(&As[row * 64 + (((ks * 2 + khalf) ^ (row & 7)) << 3)]);
            }
#pragma unroll
            for (int i = 0; i < MI; i++)
#pragma unroll
                for (int j = 0; j < 2; j++)
                    acc[i][j] = __builtin_amdgcn_mfma_f32_32x32x16_bf16(af[i], bgl[ks][j], acc[i][j], 0, 0, 0);
        }
    }

    if (MODE == 0) {
        const int wsel = n0 >> 10;
        if (wsel <= 1) {
            u16* dst = (wsel == 0) ? oQ : oK;
#pragma unroll
            for (int i = 0; i < 2; i++)
#pragma unroll
                for (int j = 0; j < 2; j++) {
                    int gn = n0 + wn * 64 + j * 32 + row32;
                    int dd = gn & 63, hh = (gn >> 6) & 15;
#pragma unroll
                    for (int reg = 0; reg < 16; reg++) {
                        int m = m0 + wm * 64 + i * 32 + (reg & 3) + 8 * (reg >> 2) + 4 * khalf;
                        int b = m >> 11, t = m & 2047;
                        dst[(size_t)(b * 16 + hh) * 131072 + t * 64 + dd] = f2b(acc[i][j][reg]);
                    }
                }
        }
        if (wsel >= 1) {
            __syncthreads();
            u16* Tl = Sh + wv * 4096;
#pragma unroll
            for (int i = 0; i < 2; i++)
#pragma unroll
                for (int j = 0; j < 2; j++) {
                    int n_loc = j * 32 + row32;
#pragma unroll
                    for (int g = 0; g < 4; g++) {
                        int m4 = i * 32 + 8 * g + 4 * khalf;
                        ull pk = (ull)f2b(acc[i][j][4 * g]) | ((ull)f2b(acc[i][j][4 * g + 1]) << 16) |
                                 ((ull)f2b(acc[i][j][4 * g + 2]) << 32) | ((ull)f2b(acc[i][j][4 * g + 3]) << 48);
                        *(ull*)(&Tl[n_loc * 64 + (((m4 >> 3) ^ (n_loc & 7)) << 3) + (m4 & 7)]) = pk;
                    }
                }
            __syncthreads();
            int gnb = n0 + wn * 64;
            int hh = (gnb >> 6) & 15;
            int mb = m0 + wm * 64;
            int bh = (mb >> 11) * 16 + hh;
            int t0 = mb & 2047;
            u16* dstT = (wsel == 1) ? oKt : oVt;
            int rr = lane >> 3, ss = lane & 7;
#pragma unroll
            for (int g = 0; g < 8; g++) {
                int row = 8 * g + rr;
                short8 v = *(const short8*)(&Tl[row * 64 + ((ss ^ rr) << 3)]);
                *(short8*)(&dstT[(size_t)bh * 131072 + (size_t)row * 2048 + t0 + ss * 8]) = v;
            }
        }
    } else {
        int gn0 = n0 + wn * 64 + row32;
        float bv0 = bias[(m0 >> 11) * 1024 + gn0];
        float bv1 = bias[(m0 >> 11) * 1024 + gn0 + 32];
#pragma unroll
        for (int i = 0; i < 2; i++)
#pragma unroll
            for (int g = 0; g < 4; g++)
#pragma unroll
                for (int rr = 0; rr < 4; rr++) {
                    int reg = 4 * g + rr;
                    int m = m0 + wm * 64 + i * 32 + 8 * g + 4 * khalf + rr;
                    of[(size_t)m * 1024 + gn0] = acc[i][0][reg] + bv0;
                    of[(size_t)m * 1024 + gn0 + 32] = acc[i][1][reg] + bv1;
                }
    }
}

// ---------------- Pass A: per-chunk summary U^T[d2][d1] = sum_b g^(63-b) V[b,d2] K[b,d1] ----
__global__ __launch_bounds__(256)
void chunk_state(const u16* __restrict__ Kt, const u16* __restrict__ Vt,
                 u16* __restrict__ U, float* __restrict__ stats)
{
    const int c = blockIdx.x, bh = blockIdx.y, h = bh & 15;
    const int tid = threadIdx.x, lane = tid & 63, w = tid >> 6;
    const int row16 = lane & 15, quad = lane >> 4;
    const float lg = lg_gamma(h);
    const size_t base = (size_t)bh * 131072;

    if (c == 0 && tid < 2) stats[2 * bh + tid] = 0.f;

    float4v acc[4];
    float4v zero4 = {0.f, 0.f, 0.f, 0.f};
#pragma unroll
    for (int tn = 0; tn < 4; tn++) acc[tn] = zero4;

#pragma unroll
    for (int kb = 0; kb < 2; kb++) {
        short8 a = *(const short8*)(Vt + base + (size_t)(16 * w + row16) * 2048 + c * 64 + kb * 32 + quad * 8);
        short8 as;
        int e0 = 63 - (kb * 32 + quad * 8);
#pragma unroll
        for (int jj = 0; jj < 8; jj++) {
            float v = b2f((u16)a[jj]) * exp2f(lg * (float)(e0 - jj));
            as[jj] = (short)f2b(v);
        }
#pragma unroll
        for (int tn = 0; tn < 4; tn++) {
            short8 bfr = *(const short8*)(Kt + base + (size_t)(16 * tn + row16) * 2048 + c * 64 + kb * 32 + quad * 8);
            acc[tn] = __builtin_amdgcn_mfma_f32_16x16x32_bf16(as, bfr, acc[tn], 0, 0, 0);
        }
    }
    u16* up = U + ((size_t)bh * 32 + c) * 4096;
#pragma unroll
    for (int tn = 0; tn < 4; tn++)
#pragma unroll
        for (int r = 0; r < 4; r++)
            up[(16 * w + quad * 4 + r) * 64 + 16 * tn + row16] = f2b(acc[tn][r]);
}

// ---------------- Pass C: intra + inter, fused one-level scan + GN sums ----
// Grid-axis SWAP (bh = x, c = y): linear block id = bh + 32*c, so each CU's 4
// resident blocks get c spread {c0, c0+8, c0+16, c0+24} -- per-CU scan work
// [48,76] iters instead of [0,124] (old c-major mapping put the SAME c on all
// 4 blocks of a CU; c=31 CUs set the kernel time while c=0 CUs idled).
__global__ __launch_bounds__(256)
void retention_chunk(const u16* __restrict__ Q, const u16* __restrict__ Kb,
                     const u16* __restrict__ Vt, const u16* __restrict__ U,
                     u16* __restrict__ Yb, float* __restrict__ stats)
{
    __shared__ __attribute__((aligned(16))) u16 Pl[4][16 * 72];
    __shared__ __attribute__((aligned(16))) u16 Sl[4096];
    __shared__ float red[8];
    const int c = blockIdx.y, bh = blockIdx.x, h = bh & 15;
    const int tid = threadIdx.x, lane = tid & 63, w = tid >> 6;
    const int row16 = lane & 15, quad = lane >> 4;
    const float lg = lg_gamma(h);
    const size_t base = (size_t)bh * 131072;
    float4v zero4 = {0.f, 0.f, 0.f, 0.f};

    short8 qf[2];
#pragma unroll
    for (int kb = 0; kb < 2; kb++)
        qf[kb] = *(const short8*)(Q + base + (size_t)(c * 64 + 16 * w + row16) * 64 + kb * 32 + quad * 8);

    // ---- fused state scan (16 indep fp32 chains/thread; loads are L2-warm) ----
    if (c != 0) {
        const float g64 = exp2f(lg * 64.0f);
        float sreg[16];
#pragma unroll
        for (int j = 0; j < 16; j++) sreg[j] = 0.f;
        for (int cp = 0; cp < c; cp++) {
            const u16* up = U + ((size_t)bh * 32 + cp) * 4096 + tid * 8;
            short8 u0 = *(const short8*)(up);
            short8 u1 = *(const short8*)(up + 2048);
#pragma unroll
            for (int jj = 0; jj < 8; jj++) {
                sreg[jj]     = g64 * sreg[jj]     + b2f((u16)u0[jj]);
                sreg[8 + jj] = g64 * sreg[8 + jj] + b2f((u16)u1[jj]);
            }
        }
#pragma unroll
        for (int j = 0; j < 2; j++) {
            int e0 = j * 2048 + tid * 8;
            int row = e0 >> 6, col8 = (e0 >> 3) & 7;
            short8 pk;
#pragma unroll
            for (int jj = 0; jj < 8; jj++) pk[jj] = (short)f2b(sreg[j * 8 + jj]);
            *(short8*)(&Sl[row * 64 + ((col8 ^ (row & 7)) << 3)]) = pk;
        }
    }

    // Phase 1: P = (Q*0.125) K^T
    float4v accp[4];
#pragma unroll
    for (int tn = 0; tn < 4; tn++) accp[tn] = zero4;
#pragma unroll
    for (int tn = 0; tn < 4; tn++)
#pragma unroll
        for (int kb = 0; kb < 2; kb++) {
            short8 kf = *(const short8*)(Kb + base + (size_t)(c * 64 + 16 * tn + row16) * 64 + kb * 32 + quad * 8);
            accp[tn] = __builtin_amdgcn_mfma_f32_16x16x32_bf16(qf[kb], kf, accp[tn], 0, 0, 0);
        }
#pragma unroll
    for (int tn = 0; tn < 4; tn++)
#pragma unroll
        for (int r = 0; r < 4; r++) {
            int a_loc = 16 * w + quad * 4 + r;
            int b_loc = 16 * tn + row16;
            int d = a_loc - b_loc;
            float v = (d >= 0) ? accp[tn][r] * exp2f(lg * (float)d) : 0.f;
            Pl[w][(quad * 4 + r) * 72 + b_loc] = f2b(v);
        }
    __syncthreads();

    short8 pf[2];
#pragma unroll
    for (int kb = 0; kb < 2; kb++)
        pf[kb] = *(const short8*)(&Pl[w][row16 * 72 + kb * 32 + quad * 8]);

    float4v acco[4], acci[4];
#pragma unroll
    for (int tn = 0; tn < 4; tn++) { acco[tn] = zero4; acci[tn] = zero4; }
#pragma unroll
    for (int tn = 0; tn < 4; tn++)
#pragma unroll
        for (int kb = 0; kb < 2; kb++) {
            short8 vf = *(const short8*)(Vt + base + (size_t)(16 * tn + row16) * 2048 + c * 64 + kb * 32 + quad * 8);
            acco[tn] = __builtin_amdgcn_mfma_f32_16x16x32_bf16(pf[kb], vf, acco[tn], 0, 0, 0);
            if (c != 0) {
                int srow = 16 * tn + row16, scol8 = kb * 4 + quad;
                short8 sf = *(const short8*)(&Sl[srow * 64 + ((scol8 ^ (srow & 7)) << 3)]);
                acci[tn] = __builtin_amdgcn_mfma_f32_16x16x32_bf16(qf[kb], sf, acci[tn], 0, 0, 0);
            }
        }

    const int b = bh >> 4;
    float s = 0.f, s2 = 0.f;
#pragma unroll
    for (int tn = 0; tn < 4; tn++)
#pragma unroll
        for (int r = 0; r < 4; r++) {
            int a_loc = 16 * w + quad * 4 + r;
            float gi = exp2f(lg * (float)(a_loc + 1));
            int t = c * 64 + a_loc, d2 = 16 * tn + row16;
            float yv = acco[tn][r] + gi * acci[tn][r];
            u16 yq = f2b(yv);
            Yb[((size_t)(b * 2048 + t)) * 1024 + h * 64 + d2] = yq;
            float yr = b2f(yq);
            s += yr;
            s2 += yr * yr;
        }
    // fused GN partial sums: wave reduce -> LDS -> one atomic pair per block
#pragma unroll
    for (int off = 32; off; off >>= 1) {
        s += __shfl_down(s, off, 64);
        s2 += __shfl_down(s2, off, 64);
    }
    if (lane == 0) { red[w] = s; red[4 + w] = s2; }
    __syncthreads();
    if (tid == 0) {
        atomicAdd(&stats[2 * bh], red[0] + red[1] + red[2] + red[3]);
        atomicAdd(&stats[2 * bh + 1], red[4] + red[5] + red[6] + red[7]);
    }
}

// ---------------- GN fold (fully parallel) ----------------
__global__ __launch_bounds__(256)
void gn_fold(const float* __restrict__ wo, const float* __restrict__ stats,
             const float* __restrict__ gnw, const float* __restrict__ gnb,
             u16* __restrict__ wob2, float* __restrict__ bias)
{
    int bid = blockIdx.x;
    int lane = threadIdx.x & 63, wvid = threadIdx.x >> 6;
    if (bid < 512) {
        int seg = bid * 4 + wvid;
        int panel = seg >> 6, kg = seg & 63;
        int row = lane & 31, kh = lane >> 5;
        int c0 = kg * 16 + kh * 8;
        int hh = c0 >> 6;
        const float* srow = wo + (size_t)(panel * 32 + row) * 1024 + c0;
        float4 a = *(const float4*)(srow);
        float4 b = *(const float4*)(srow + 4);
        float4 w0 = *(const float4*)(gnw + c0);
        float4 w1 = *(const float4*)(gnw + c0 + 4);
        size_t off = (size_t)panel * 32768 + kg * 512 + lane * 8;
#pragma unroll
        for (int bb = 0; bb < 2; bb++) {
            int bh = bb * 16 + hh;
            float S = stats[2 * bh], S2 = stats[2 * bh + 1];
            float mu = S * (1.0f / 131072.f);
            float rsg = rsqrtf(S2 * (1.0f / 131072.f) - mu * mu + 1e-5f);
            short8 o;
            o[0] = (short)f2b(a.x * rsg * w0.x); o[1] = (short)f2b(a.y * rsg * w0.y);
            o[2] = (short)f2b(a.z * rsg * w0.z); o[3] = (short)f2b(a.w * rsg * w0.w);
            o[4] = (short)f2b(b.x * rsg * w1.x); o[5] = (short)f2b(b.y * rsg * w1.y);
            o[6] = (short)f2b(b.z * rsg * w1.z); o[7] = (short)f2b(b.w * rsg * w1.w);
            *(short8*)(wob2 + (size_t)bb * 1048576 + off) = o;
        }
    } else {
        int t = (bid - 512) * 4 + wvid;
        int bb = t >> 10, n = t & 1023;
        int c0 = lane * 16;
        int bh = bb * 16 + (c0 >> 6);
        float S = stats[2 * bh], S2 = stats[2 * bh + 1];
        float mu = S * (1.0f / 131072.f);
        float rsg = rsqrtf(S2 * (1.0f / 131072.f) - mu * mu + 1e-5f);
        const float* wrow = wo + (size_t)n * 1024 + c0;
        float acc = 0.f;
#pragma unroll
        for (int cc = 0; cc < 16; cc += 4) {
            float4 wo4 = *(const float4*)(wrow + cc);
            float4 w4 = *(const float4*)(gnw + c0 + cc);
            float4 b4 = *(const float4*)(gnb + c0 + cc);
            acc += (b4.x - mu * rsg * w4.x) * wo4.x + (b4.y - mu * rsg * w4.y) * wo4.y
                 + (b4.z - mu * rsg * w4.z) * wo4.z + (b4.w - mu * rsg * w4.w) * wo4.w;
        }
#pragma unroll
        for (int off = 32; off; off >>= 1) acc += __shfl_down(acc, off, 64);
        if (lane == 0) bias[t] = acc;
    }
}

extern "C" void kernel_launch(void* const* d_in, const int* in_sizes, int n_in,
                              void* d_out, int out_size, void* d_ws, size_t ws_size,
                              hipStream_t stream) {
    const float* x   = (const float*)d_in[0];
    const float* Wq  = (const float*)d_in[1];
    const float* Wk  = (const float*)d_in[2];
    const float* Wv  = (const float*)d_in[3];
    const float* Wo  = (const float*)d_in[4];
    const float* gnw = (const float*)d_in[5];
    const float* gnb = (const float*)d_in[6];
    float* out = (float*)d_out;
    char* ws = (char*)d_ws;

    u16*  xb    = (u16*)(ws + 0);           // 8 MB
    u16*  wqkvb = (u16*)(ws + 8388608);     // 6 MB
    u16*  Qs    = (u16*)(ws + 16777216);    // 8 MB
    u16*  Kb    = (u16*)(ws + 25165824);    // 8 MB
    u16*  Kt    = (u16*)(ws + 33554432);    // 8 MB
    u16*  Vt    = (u16*)(ws + 41943040);    // 8 MB
    u16*  U     = (u16*)(ws + 50331648);    // 8 MB
    u16*  Yb    = (u16*)(ws + 67108864);    // 8 MB
    u16*  wob2  = (u16*)(ws + 75497472);    // 4 MB
    float* bias = (float*)(ws + 79691776);  // 8 KB
    float* stats= (float*)(ws + 100663296); // 256 B

    cvt_all<<<5632, 256, 0, stream>>>(x, Wq, Wk, Wv, xb, wqkvb);

    gemm_nt<0><<<dim3(24, 32), 256, 0, stream>>>(xb, wqkvb, Qs, Kb, Kt, Vt, nullptr, nullptr);

    chunk_state<<<dim3(32, 32), 256, 0, stream>>>(Kt, Vt, U, stats);
    retention_chunk<<<dim3(32, 32), 256, 0, stream>>>(Qs, Kb, Vt, U, Yb, stats);

    gn_fold<<<1024, 256, 0, stream>>>(Wo, stats, gnw, gnb, wob2, bias);

    gemm_nt<1><<<dim3(8, 32), 256, 0, stream>>>(Yb, wob2, nullptr, nullptr, nullptr, nullptr, out, bias);
}